// Round 18
// baseline (52.467 us; speedup 1.0000x reference)
//
#include <hip/hip_runtime.h>
#include <math.h>

// MultiHeadAttentionQuantum: analytic collapse of the 8-qubit circuit.
//   angles[t][n] = dot(x[t], w_q[n]) + q_params[n] ; c = cos(angles)
//   z[0] = c1..c7 ; z[w>=1] = c0..cw  (Heisenberg CNOT-ring push-through)
//   out[t][e] = sum_n z[n] * w_out[e][n]
//
// R18: five schedules all pin at 4.0-4.1 TB/s -> the fused kernel's
// fine-grained read/write interleave is the limiter, not the schedule.
// Phase-separated split (R3 redone WITHOUT its diseases): k1 = pure-read
// dot+circuit8 -> z (1 MB scratch, L2-resident); k2 = pure-write rank-8
// expansion, w_out^T in LDS (not global: R7 disease), plain stores (R13),
// circuit8 (not R3's slow reduction). Fallback to fused R13 if ws < 1 MB.

using f32x4 = __attribute__((ext_vector_type(4))) float;

constexpr int E  = 768;
constexpr int NW = 8;
constexpr int BLOCK = 256;                      // 4 waves
constexpr int TOKENS = 16 * 2048;               // 32768
constexpr int TOK_PER_WAVE  = 4;
constexpr int TOK_PER_BLOCK = TOK_PER_WAVE * 4; // 16
constexpr int GRID = TOKENS / TOK_PER_BLOCK;    // 2048

__device__ __forceinline__ float dot12(const f32x4& a0, const f32x4& a1, const f32x4& a2,
                                       const f32x4& b0, const f32x4& b1, const f32x4& b2) {
    return a0.x*b0.x + a0.y*b0.y + a0.z*b0.z + a0.w*b0.w
         + a1.x*b1.x + a1.y*b1.y + a1.z*b1.z + a1.w*b1.w
         + a2.x*b2.x + a2.y*b2.y + a2.z*b2.z + a2.w*b2.w;
}

// Wave-wide reduce of zf[0..7] + cos + CNOT-ring prefix products.
// Numerically verified R4-R17 (absmax 0.0078).
__device__ __forceinline__ void circuit8(const float zf[NW], int lane, float qpl,
                                         float z[NW]) {
    float v4[4];
    #pragma unroll
    for (int i = 0; i < 4; ++i) {
        float a = zf[2*i], b = zf[2*i+1];
        float keep = (lane & 1) ? b : a;
        float send = (lane & 1) ? a : b;
        v4[i] = keep + __shfl_xor(send, 1, 64);
    }
    float v2[2];
    #pragma unroll
    for (int i = 0; i < 2; ++i) {
        float a = v4[2*i], b = v4[2*i+1];
        float keep = (lane & 2) ? b : a;
        float send = (lane & 2) ? a : b;
        v2[i] = keep + __shfl_xor(send, 2, 64);
    }
    float a = v2[0], b = v2[1];
    float keep = (lane & 4) ? b : a;
    float send = (lane & 4) ? a : b;
    float v = keep + __shfl_xor(send, 4, 64);
    v += __shfl_xor(v, 8, 64);
    v += __shfl_xor(v, 16, 64);
    v += __shfl_xor(v, 32, 64);
    float c = __cosf(v + qpl);               // one cos per token (wire lane&7)
    float cx = __shfl_xor(c, 1, 64);
    float e0 = (lane & 1) ? cx : c;
    float e1 = (lane & 1) ? c : cx;
    float e0x = __shfl_xor(e0, 2, 64), e1x = __shfl_xor(e1, 2, 64);
    float f0 = (lane & 2) ? e0x : e0;
    float f1 = (lane & 2) ? e1x : e1;
    float f2 = (lane & 2) ? e0  : e0x;
    float f3 = (lane & 2) ? e1  : e1x;
    float f0x = __shfl_xor(f0, 4, 64), f1x = __shfl_xor(f1, 4, 64);
    float f2x = __shfl_xor(f2, 4, 64), f3x = __shfl_xor(f3, 4, 64);
    float c0 = (lane & 4) ? f0x : f0;
    float c1 = (lane & 4) ? f1x : f1;
    float c2 = (lane & 4) ? f2x : f2;
    float c3 = (lane & 4) ? f3x : f3;
    float c4 = (lane & 4) ? f0  : f0x;
    float c5 = (lane & 4) ? f1  : f1x;
    float c6 = (lane & 4) ? f2  : f2x;
    float c7 = (lane & 4) ? f3  : f3x;
    float p1 = c0*c1, p2 = p1*c2, p3 = p2*c3, p4 = p3*c4;
    float p5 = p4*c5, p6 = p5*c6, p7 = p6*c7;
    float s  = c1*c2*c3*c4*c5*c6*c7;
    z[0] = s;  z[1] = p1; z[2] = p2; z[3] = p3;
    z[4] = p4; z[5] = p5; z[6] = p6; z[7] = p7;
}

// ---------------- Kernel 1 (read stream): z = circuit(x.w_q + qp) -----------
__global__ __launch_bounds__(BLOCK, 4)
void zcalc_kernel(const float* __restrict__ x,
                  const float* __restrict__ w_q,
                  const float* __restrict__ q_params,
                  float* __restrict__ zout)          // [TOKENS][NW]
{
    __shared__ float wq_lds[NW][E];   // 24 KB

    const int tid  = threadIdx.x;
    const int wave = tid >> 6;
    const int lane = tid & 63;
    const int col  = lane * 4;
    const int t0   = blockIdx.x * TOK_PER_BLOCK + wave * TOK_PER_WAVE;

    // x loads first (HBM latency overlaps staging)
    f32x4 xv[TOK_PER_WAVE][3];
    #pragma unroll
    for (int tt = 0; tt < TOK_PER_WAVE; ++tt) {
        const f32x4* xp = reinterpret_cast<const f32x4*>(x + (size_t)(t0 + tt) * E);
        #pragma unroll
        for (int k = 0; k < 3; ++k)
            xv[tt][k] = xp[lane + k * 64];
    }
    {
        const f32x4* src = reinterpret_cast<const f32x4*>(w_q);
        f32x4* dst = reinterpret_cast<f32x4*>(&wq_lds[0][0]);
        #pragma unroll
        for (int r = 0; r < (NW * E / 4) / BLOCK; ++r)
            dst[tid + r * BLOCK] = src[tid + r * BLOCK];
    }
    const float qpl = q_params[lane & 7];
    __syncthreads();

    float zf[TOK_PER_WAVE][NW];
    #pragma unroll
    for (int n = 0; n < NW; ++n) {
        const f32x4 w0 = *reinterpret_cast<const f32x4*>(&wq_lds[n][col]);
        const f32x4 w1 = *reinterpret_cast<const f32x4*>(&wq_lds[n][col + 256]);
        const f32x4 w2 = *reinterpret_cast<const f32x4*>(&wq_lds[n][col + 512]);
        #pragma unroll
        for (int tt = 0; tt < TOK_PER_WAVE; ++tt)
            zf[tt][n] = dot12(xv[tt][0], xv[tt][1], xv[tt][2], w0, w1, w2);
    }

    float z[TOK_PER_WAVE][NW];
    #pragma unroll
    for (int tt = 0; tt < TOK_PER_WAVE; ++tt)
        circuit8(zf[tt], lane, qpl, z[tt]);

    // lane<32 stores zout[t0*8 + lane] = z[lane>>3][lane&7] -- static select
    // tree, verified in R3.
    float sel[NW];
    #pragma unroll
    for (int n = 0; n < NW; ++n) {
        float s01 = (lane & 8)  ? z[1][n] : z[0][n];
        float s23 = (lane & 8)  ? z[3][n] : z[2][n];
        sel[n]    = (lane & 16) ? s23 : s01;
    }
    float v01 = (lane & 1) ? sel[1] : sel[0];
    float v23 = (lane & 1) ? sel[3] : sel[2];
    float v45 = (lane & 1) ? sel[5] : sel[4];
    float v67 = (lane & 1) ? sel[7] : sel[6];
    float v03 = (lane & 2) ? v23 : v01;
    float v47 = (lane & 2) ? v67 : v45;
    float vv  = (lane & 4) ? v47 : v03;
    if (lane < 32) zout[(size_t)t0 * NW + lane] = vv;   // 128B contiguous / wave
}

// ---------------- Kernel 2 (write stream): out = z . w_out^T ----------------
__global__ __launch_bounds__(BLOCK, 4)
void expand_kernel(const float* __restrict__ z,
                   const float* __restrict__ w_out,
                   float* __restrict__ out)
{
    __shared__ float wt_lds[NW][E];   // 24 KB, w_out transposed [n][e]

    const int tid  = threadIdx.x;
    const int wave = tid >> 6;
    const int lane = tid & 63;
    const int col  = lane * 4;

    {
        const f32x4* src = reinterpret_cast<const f32x4*>(w_out);
        #pragma unroll
        for (int r = 0; r < (NW * E / 4) / BLOCK; ++r) {
            int idx = tid + r * BLOCK;       // f32x4 index into [768][8]
            f32x4 v = src[idx];
            int e  = idx >> 1;
            int n0 = (idx & 1) * 4;
            wt_lds[n0 + 0][e] = v.x;
            wt_lds[n0 + 1][e] = v.y;
            wt_lds[n0 + 2][e] = v.z;
            wt_lds[n0 + 3][e] = v.w;
        }
    }
    __syncthreads();

    const int t0u = __builtin_amdgcn_readfirstlane(
        blockIdx.x * TOK_PER_BLOCK + wave * TOK_PER_WAVE);

    // z: 4 tokens x 8 floats, wave-uniform -> scalar loads (L2-hot, 1 MB total)
    float zz[TOK_PER_WAVE][NW];
    #pragma unroll
    for (int tt = 0; tt < TOK_PER_WAVE; ++tt) {
        #pragma unroll
        for (int n = 0; n < NW; ++n)
            zz[tt][n] = z[(size_t)(t0u + tt) * NW + n];
    }

    #pragma unroll
    for (int k = 0; k < 3; ++k) {
        const int e0 = k * 256 + col;
        f32x4 wv[NW];
        #pragma unroll
        for (int n = 0; n < NW; ++n)
            wv[n] = *reinterpret_cast<const f32x4*>(&wt_lds[n][e0]);
        #pragma unroll
        for (int tt = 0; tt < TOK_PER_WAVE; ++tt) {
            float ox = 0.f, oy = 0.f, oz = 0.f, ow = 0.f;
            #pragma unroll
            for (int n = 0; n < NW; ++n) {
                ox += zz[tt][n] * wv[n].x;
                oy += zz[tt][n] * wv[n].y;
                oz += zz[tt][n] * wv[n].z;
                ow += zz[tt][n] * wv[n].w;
            }
            f32x4 o; o.x = ox; o.y = oy; o.z = oz; o.w = ow;
            *reinterpret_cast<f32x4*>(out + (size_t)(t0u + tt) * E + e0) = o;
        }
    }
}

// ---------------- Fallback: fused R13 if ws too small -----------------------
__global__ __launch_bounds__(BLOCK, 4)
void mhaq_fused(const float* __restrict__ x,
                const float* __restrict__ w_q,
                const float* __restrict__ w_out,
                const float* __restrict__ q_params,
                float* __restrict__ out)
{
    __shared__ float wq_lds[NW][E];
    __shared__ float wt_lds[NW][E];

    const int tid  = threadIdx.x;
    const int wave = tid >> 6;
    const int lane = tid & 63;
    const int col  = lane * 4;
    const int t0   = blockIdx.x * TOK_PER_BLOCK + wave * TOK_PER_WAVE;

    f32x4 xv[TOK_PER_WAVE][3];
    #pragma unroll
    for (int tt = 0; tt < TOK_PER_WAVE; ++tt) {
        const f32x4* xp = reinterpret_cast<const f32x4*>(x + (size_t)(t0 + tt) * E);
        #pragma unroll
        for (int k = 0; k < 3; ++k)
            xv[tt][k] = xp[lane + k * 64];
    }
    {
        const f32x4* src = reinterpret_cast<const f32x4*>(w_q);
        f32x4* dst = reinterpret_cast<f32x4*>(&wq_lds[0][0]);
        #pragma unroll
        for (int r = 0; r < (NW * E / 4) / BLOCK; ++r)
            dst[tid + r * BLOCK] = src[tid + r * BLOCK];
    }
    {
        const f32x4* src = reinterpret_cast<const f32x4*>(w_out);
        #pragma unroll
        for (int r = 0; r < (NW * E / 4) / BLOCK; ++r) {
            int idx = tid + r * BLOCK;
            f32x4 v = src[idx];
            int e  = idx >> 1;
            int n0 = (idx & 1) * 4;
            wt_lds[n0 + 0][e] = v.x;
            wt_lds[n0 + 1][e] = v.y;
            wt_lds[n0 + 2][e] = v.z;
            wt_lds[n0 + 3][e] = v.w;
        }
    }
    const float qpl = q_params[lane & 7];
    __syncthreads();

    float zf[TOK_PER_WAVE][NW];
    #pragma unroll
    for (int n = 0; n < NW; ++n) {
        const f32x4 w0 = *reinterpret_cast<const f32x4*>(&wq_lds[n][col]);
        const f32x4 w1 = *reinterpret_cast<const f32x4*>(&wq_lds[n][col + 256]);
        const f32x4 w2 = *reinterpret_cast<const f32x4*>(&wq_lds[n][col + 512]);
        #pragma unroll
        for (int tt = 0; tt < TOK_PER_WAVE; ++tt)
            zf[tt][n] = dot12(xv[tt][0], xv[tt][1], xv[tt][2], w0, w1, w2);
    }
    float z[TOK_PER_WAVE][NW];
    #pragma unroll
    for (int tt = 0; tt < TOK_PER_WAVE; ++tt)
        circuit8(zf[tt], lane, qpl, z[tt]);

    #pragma unroll
    for (int k = 0; k < 3; ++k) {
        const int e0 = k * 256 + col;
        f32x4 wv[NW];
        #pragma unroll
        for (int n = 0; n < NW; ++n)
            wv[n] = *reinterpret_cast<const f32x4*>(&wt_lds[n][e0]);
        #pragma unroll
        for (int tt = 0; tt < TOK_PER_WAVE; ++tt) {
            float ox = 0.f, oy = 0.f, oz = 0.f, ow = 0.f;
            #pragma unroll
            for (int n = 0; n < NW; ++n) {
                ox += z[tt][n] * wv[n].x;
                oy += z[tt][n] * wv[n].y;
                oz += z[tt][n] * wv[n].z;
                ow += z[tt][n] * wv[n].w;
            }
            f32x4 o; o.x = ox; o.y = oy; o.z = oz; o.w = ow;
            *reinterpret_cast<f32x4*>(out + (size_t)(t0 + tt) * E + e0) = o;
        }
    }
}

extern "C" void kernel_launch(void* const* d_in, const int* in_sizes, int n_in,
                              void* d_out, int out_size, void* d_ws, size_t ws_size,
                              hipStream_t stream) {
    const float* x        = (const float*)d_in[0];
    const float* w_q      = (const float*)d_in[1];
    const float* w_out    = (const float*)d_in[2];
    const float* q_params = (const float*)d_in[3];
    float* out = (float*)d_out;

    const size_t z_bytes = (size_t)TOKENS * NW * sizeof(float);
    if (ws_size >= z_bytes) {
        float* z = (float*)d_ws;
        hipLaunchKernelGGL(zcalc_kernel,  dim3(GRID), dim3(BLOCK), 0, stream,
                           x, w_q, q_params, z);
        hipLaunchKernelGGL(expand_kernel, dim3(GRID), dim3(BLOCK), 0, stream,
                           z, w_out, out);
    } else {
        hipLaunchKernelGGL(mhaq_fused, dim3(GRID), dim3(BLOCK), 0, stream,
                           x, w_q, w_out, q_params, out);
    }
}

// Round 19
// 40.355 us; speedup vs baseline: 1.3001x; 1.3001x over previous
//
#include <hip/hip_runtime.h>
#include <math.h>

// MultiHeadAttentionQuantum: analytic collapse of the 8-qubit circuit.
//   angles[t][n] = dot(x[t], w_q[n]) + q_params[n] ; c = cos(angles)
//   z[0] = c1..c7 ; z[w>=1] = c0..cw  (Heisenberg CNOT-ring push-through)
//   out[t][e] = sum_n z[n] * w_out[e][n]
//
// R19: R18 split regressed (52.5us) -- stream separation falsified. Audit
// shows "occupancy irrelevant" was never cleanly tested: every high-occ
// config was confounded (spill / global weights / +30% instructions).
// R12's BLOCK=512 failed ONLY because bounds(512,4) squeezed VGPR 72->64.
// This round: R13 byte-identical per-wave stream, BLOCK=512 with
// __launch_bounds__(512) ONLY (no min-waves arg -> natural ~72 VGPR),
// grid 1024 -> 3 blocks/CU x 8 waves = 24 waves/CU, 2x R13's residency,
// staging amortized 2x.

using f32x4 = __attribute__((ext_vector_type(4))) float;

constexpr int E  = 768;
constexpr int NW = 8;
constexpr int BLOCK = 512;                      // 8 waves
constexpr int TOKENS = 16 * 2048;               // 32768
constexpr int TOK_PER_WAVE  = 4;
constexpr int TOK_PER_BLOCK = TOK_PER_WAVE * 8; // 32
constexpr int GRID = TOKENS / TOK_PER_BLOCK;    // 1024

__device__ __forceinline__ float dot12(const f32x4& a0, const f32x4& a1, const f32x4& a2,
                                       const f32x4& b0, const f32x4& b1, const f32x4& b2) {
    return a0.x*b0.x + a0.y*b0.y + a0.z*b0.z + a0.w*b0.w
         + a1.x*b1.x + a1.y*b1.y + a1.z*b1.z + a1.w*b1.w
         + a2.x*b2.x + a2.y*b2.y + a2.z*b2.z + a2.w*b2.w;
}

// Wave-wide reduce of zf[0..7] + cos + CNOT-ring prefix products.
// Numerically verified R4-R18 (absmax 0.0078).
__device__ __forceinline__ void circuit8(const float zf[NW], int lane, float qpl,
                                         float z[NW]) {
    float v4[4];
    #pragma unroll
    for (int i = 0; i < 4; ++i) {
        float a = zf[2*i], b = zf[2*i+1];
        float keep = (lane & 1) ? b : a;
        float send = (lane & 1) ? a : b;
        v4[i] = keep + __shfl_xor(send, 1, 64);
    }
    float v2[2];
    #pragma unroll
    for (int i = 0; i < 2; ++i) {
        float a = v4[2*i], b = v4[2*i+1];
        float keep = (lane & 2) ? b : a;
        float send = (lane & 2) ? a : b;
        v2[i] = keep + __shfl_xor(send, 2, 64);
    }
    float a = v2[0], b = v2[1];
    float keep = (lane & 4) ? b : a;
    float send = (lane & 4) ? a : b;
    float v = keep + __shfl_xor(send, 4, 64);
    v += __shfl_xor(v, 8, 64);
    v += __shfl_xor(v, 16, 64);
    v += __shfl_xor(v, 32, 64);
    float c = __cosf(v + qpl);               // one cos per token (wire lane&7)
    float cx = __shfl_xor(c, 1, 64);
    float e0 = (lane & 1) ? cx : c;
    float e1 = (lane & 1) ? c : cx;
    float e0x = __shfl_xor(e0, 2, 64), e1x = __shfl_xor(e1, 2, 64);
    float f0 = (lane & 2) ? e0x : e0;
    float f1 = (lane & 2) ? e1x : e1;
    float f2 = (lane & 2) ? e0  : e0x;
    float f3 = (lane & 2) ? e1  : e1x;
    float f0x = __shfl_xor(f0, 4, 64), f1x = __shfl_xor(f1, 4, 64);
    float f2x = __shfl_xor(f2, 4, 64), f3x = __shfl_xor(f3, 4, 64);
    float c0 = (lane & 4) ? f0x : f0;
    float c1 = (lane & 4) ? f1x : f1;
    float c2 = (lane & 4) ? f2x : f2;
    float c3 = (lane & 4) ? f3x : f3;
    float c4 = (lane & 4) ? f0  : f0x;
    float c5 = (lane & 4) ? f1  : f1x;
    float c6 = (lane & 4) ? f2  : f2x;
    float c7 = (lane & 4) ? f3  : f3x;
    float p1 = c0*c1, p2 = p1*c2, p3 = p2*c3, p4 = p3*c4;
    float p5 = p4*c5, p6 = p5*c6, p7 = p6*c7;
    float s  = c1*c2*c3*c4*c5*c6*c7;
    z[0] = s;  z[1] = p1; z[2] = p2; z[3] = p3;
    z[4] = p4; z[5] = p5; z[6] = p6; z[7] = p7;
}

__global__ __launch_bounds__(BLOCK)
void mhaq_kernel(const float* __restrict__ x,
                 const float* __restrict__ w_q,
                 const float* __restrict__ w_out,
                 const float* __restrict__ q_params,
                 float* __restrict__ out)
{
    __shared__ float wq_lds[NW][E];   // 24 KB, w_q as-is [n][e]
    __shared__ float wt_lds[NW][E];   // 24 KB, w_out transposed [n][e]

    const int tid  = threadIdx.x;
    const int wave = tid >> 6;
    const int lane = tid & 63;
    const int col  = lane * 4;
    const int t0   = blockIdx.x * TOK_PER_BLOCK + wave * TOK_PER_WAVE;

    // ---- x loads issued FIRST: HBM latency overlaps (L2-hit) staging ----
    f32x4 xv[TOK_PER_WAVE][3];
    #pragma unroll
    for (int tt = 0; tt < TOK_PER_WAVE; ++tt) {
        const f32x4* xp = reinterpret_cast<const f32x4*>(x + (size_t)(t0 + tt) * E);
        #pragma unroll
        for (int k = 0; k < 3; ++k)
            xv[tt][k] = xp[lane + k * 64];
    }

    // ---- stage weights once per block (3 f32x4 per thread each) ----
    {
        const f32x4* src = reinterpret_cast<const f32x4*>(w_q);
        f32x4* dst = reinterpret_cast<f32x4*>(&wq_lds[0][0]);
        #pragma unroll
        for (int r = 0; r < (NW * E / 4) / BLOCK; ++r)
            dst[tid + r * BLOCK] = src[tid + r * BLOCK];
    }
    {
        const f32x4* src = reinterpret_cast<const f32x4*>(w_out);
        #pragma unroll
        for (int r = 0; r < (NW * E / 4) / BLOCK; ++r) {
            int idx = tid + r * BLOCK;       // f32x4 index into [768][8]
            f32x4 v = src[idx];
            int e  = idx >> 1;               // two f32x4 per e-row
            int n0 = (idx & 1) * 4;
            wt_lds[n0 + 0][e] = v.x;
            wt_lds[n0 + 1][e] = v.y;
            wt_lds[n0 + 2][e] = v.z;
            wt_lds[n0 + 3][e] = v.w;
        }
    }
    const float qpl = q_params[lane & 7];
    __syncthreads();

    // ---- per-lane partial dots (w_q from LDS) ----
    float zf[TOK_PER_WAVE][NW];
    #pragma unroll
    for (int n = 0; n < NW; ++n) {
        const f32x4 w0 = *reinterpret_cast<const f32x4*>(&wq_lds[n][col]);
        const f32x4 w1 = *reinterpret_cast<const f32x4*>(&wq_lds[n][col + 256]);
        const f32x4 w2 = *reinterpret_cast<const f32x4*>(&wq_lds[n][col + 512]);
        #pragma unroll
        for (int tt = 0; tt < TOK_PER_WAVE; ++tt)
            zf[tt][n] = dot12(xv[tt][0], xv[tt][1], xv[tt][2], w0, w1, w2);
    }

    // ---- wave reduce + cos + prefix products ----
    float z[TOK_PER_WAVE][NW];
    #pragma unroll
    for (int tt = 0; tt < TOK_PER_WAVE; ++tt)
        circuit8(zf[tt], lane, qpl, z[tt]);

    // ---- epilogue: out[t][e] = sum_n z[n] * w_out[e][n] (w_out from LDS),
    //      plain stores (R13) ----
    #pragma unroll
    for (int k = 0; k < 3; ++k) {
        const int e0 = k * 256 + col;
        f32x4 wv[NW];
        #pragma unroll
        for (int n = 0; n < NW; ++n)
            wv[n] = *reinterpret_cast<const f32x4*>(&wt_lds[n][e0]);
        #pragma unroll
        for (int tt = 0; tt < TOK_PER_WAVE; ++tt) {
            float ox = 0.f, oy = 0.f, oz = 0.f, ow = 0.f;
            #pragma unroll
            for (int n = 0; n < NW; ++n) {
                ox += z[tt][n] * wv[n].x;
                oy += z[tt][n] * wv[n].y;
                oz += z[tt][n] * wv[n].z;
                ow += z[tt][n] * wv[n].w;
            }
            f32x4 o; o.x = ox; o.y = oy; o.z = oz; o.w = ow;
            *reinterpret_cast<f32x4*>(out + (size_t)(t0 + tt) * E + e0) = o;
        }
    }
}

extern "C" void kernel_launch(void* const* d_in, const int* in_sizes, int n_in,
                              void* d_out, int out_size, void* d_ws, size_t ws_size,
                              hipStream_t stream) {
    const float* x        = (const float*)d_in[0];
    const float* w_q      = (const float*)d_in[1];
    const float* w_out    = (const float*)d_in[2];
    const float* q_params = (const float*)d_in[3];
    float* out = (float*)d_out;

    hipLaunchKernelGGL(mhaq_kernel, dim3(GRID), dim3(BLOCK), 0, stream,
                       x, w_q, w_out, q_params, out);
}

// Round 20
// 39.539 us; speedup vs baseline: 1.3270x; 1.0206x over previous
//
#include <hip/hip_runtime.h>
#include <math.h>

// MultiHeadAttentionQuantum: analytic collapse of the 8-qubit circuit.
//   angles[t][n] = dot(x[t], w_q[n]) + q_params[n] ; c = cos(angles)
//   z[0] = c1..c7 ; z[w>=1] = c0..cw  (Heisenberg CNOT-ring push-through)
//   out[t][e] = sum_n z[n] * w_out[e][n]
//
// R20: R19 cleanly falsified occupancy (24 waves/CU, no spill -> WORSE).
// Last unprobed term: per-token DS-pipe cost (R15 doubled wq reads -> +1.3us;
// R14 doubled LDS insts -> +8us). This round halves it: 8 tokens/wave,
// grid 1024, launch_bounds(256) with NO min-arg (R19-proven: avoids the
// allocator squeeze that killed R4/R5/R11/R12). wq/wt fragment reads and
// staging amortized 2x per token. Everything else = R13 (best, 36.1us).

using f32x4 = __attribute__((ext_vector_type(4))) float;

constexpr int E  = 768;
constexpr int NW = 8;
constexpr int BLOCK = 256;                      // 4 waves
constexpr int TOKENS = 16 * 2048;               // 32768
constexpr int TOK_PER_WAVE  = 8;
constexpr int TOK_PER_BLOCK = TOK_PER_WAVE * 4; // 32
constexpr int GRID = TOKENS / TOK_PER_BLOCK;    // 1024

__device__ __forceinline__ float dot12(const f32x4& a0, const f32x4& a1, const f32x4& a2,
                                       const f32x4& b0, const f32x4& b1, const f32x4& b2) {
    return a0.x*b0.x + a0.y*b0.y + a0.z*b0.z + a0.w*b0.w
         + a1.x*b1.x + a1.y*b1.y + a1.z*b1.z + a1.w*b1.w
         + a2.x*b2.x + a2.y*b2.y + a2.z*b2.z + a2.w*b2.w;
}

// Wave-wide reduce of zf[0..7] + cos + CNOT-ring prefix products.
// Numerically verified R4-R19 (absmax 0.0078).
__device__ __forceinline__ void circuit8(const float zf[NW], int lane, float qpl,
                                         float z[NW]) {
    float v4[4];
    #pragma unroll
    for (int i = 0; i < 4; ++i) {
        float a = zf[2*i], b = zf[2*i+1];
        float keep = (lane & 1) ? b : a;
        float send = (lane & 1) ? a : b;
        v4[i] = keep + __shfl_xor(send, 1, 64);
    }
    float v2[2];
    #pragma unroll
    for (int i = 0; i < 2; ++i) {
        float a = v4[2*i], b = v4[2*i+1];
        float keep = (lane & 2) ? b : a;
        float send = (lane & 2) ? a : b;
        v2[i] = keep + __shfl_xor(send, 2, 64);
    }
    float a = v2[0], b = v2[1];
    float keep = (lane & 4) ? b : a;
    float send = (lane & 4) ? a : b;
    float v = keep + __shfl_xor(send, 4, 64);
    v += __shfl_xor(v, 8, 64);
    v += __shfl_xor(v, 16, 64);
    v += __shfl_xor(v, 32, 64);
    float c = __cosf(v + qpl);               // one cos per token (wire lane&7)
    float cx = __shfl_xor(c, 1, 64);
    float e0 = (lane & 1) ? cx : c;
    float e1 = (lane & 1) ? c : cx;
    float e0x = __shfl_xor(e0, 2, 64), e1x = __shfl_xor(e1, 2, 64);
    float f0 = (lane & 2) ? e0x : e0;
    float f1 = (lane & 2) ? e1x : e1;
    float f2 = (lane & 2) ? e0  : e0x;
    float f3 = (lane & 2) ? e1  : e1x;
    float f0x = __shfl_xor(f0, 4, 64), f1x = __shfl_xor(f1, 4, 64);
    float f2x = __shfl_xor(f2, 4, 64), f3x = __shfl_xor(f3, 4, 64);
    float c0 = (lane & 4) ? f0x : f0;
    float c1 = (lane & 4) ? f1x : f1;
    float c2 = (lane & 4) ? f2x : f2;
    float c3 = (lane & 4) ? f3x : f3;
    float c4 = (lane & 4) ? f0  : f0x;
    float c5 = (lane & 4) ? f1  : f1x;
    float c6 = (lane & 4) ? f2  : f2x;
    float c7 = (lane & 4) ? f3  : f3x;
    float p1 = c0*c1, p2 = p1*c2, p3 = p2*c3, p4 = p3*c4;
    float p5 = p4*c5, p6 = p5*c6, p7 = p6*c7;
    float s  = c1*c2*c3*c4*c5*c6*c7;
    z[0] = s;  z[1] = p1; z[2] = p2; z[3] = p3;
    z[4] = p4; z[5] = p5; z[6] = p6; z[7] = p7;
}

__global__ __launch_bounds__(BLOCK)
void mhaq_kernel(const float* __restrict__ x,
                 const float* __restrict__ w_q,
                 const float* __restrict__ w_out,
                 const float* __restrict__ q_params,
                 float* __restrict__ out)
{
    __shared__ float wq_lds[NW][E];   // 24 KB, w_q as-is [n][e]
    __shared__ float wt_lds[NW][E];   // 24 KB, w_out transposed [n][e]

    const int tid  = threadIdx.x;
    const int wave = tid >> 6;
    const int lane = tid & 63;
    const int col  = lane * 4;
    const int t0   = blockIdx.x * TOK_PER_BLOCK + wave * TOK_PER_WAVE;

    // ---- x loads issued FIRST: HBM latency overlaps (L2-hit) staging ----
    f32x4 xv[TOK_PER_WAVE][3];
    #pragma unroll
    for (int tt = 0; tt < TOK_PER_WAVE; ++tt) {
        const f32x4* xp = reinterpret_cast<const f32x4*>(x + (size_t)(t0 + tt) * E);
        #pragma unroll
        for (int k = 0; k < 3; ++k)
            xv[tt][k] = xp[lane + k * 64];
    }

    // ---- stage weights once per block ----
    {
        const f32x4* src = reinterpret_cast<const f32x4*>(w_q);
        f32x4* dst = reinterpret_cast<f32x4*>(&wq_lds[0][0]);
        #pragma unroll
        for (int r = 0; r < (NW * E / 4) / BLOCK; ++r)
            dst[tid + r * BLOCK] = src[tid + r * BLOCK];
    }
    {
        const f32x4* src = reinterpret_cast<const f32x4*>(w_out);
        #pragma unroll
        for (int r = 0; r < (NW * E / 4) / BLOCK; ++r) {
            int idx = tid + r * BLOCK;       // f32x4 index into [768][8]
            f32x4 v = src[idx];
            int e  = idx >> 1;               // two f32x4 per e-row
            int n0 = (idx & 1) * 4;
            wt_lds[n0 + 0][e] = v.x;
            wt_lds[n0 + 1][e] = v.y;
            wt_lds[n0 + 2][e] = v.z;
            wt_lds[n0 + 3][e] = v.w;
        }
    }
    const float qpl = q_params[lane & 7];
    __syncthreads();

    // ---- per-lane partial dots: wq fragments read ONCE per 8 tokens ----
    float zf[TOK_PER_WAVE][NW];
    #pragma unroll
    for (int n = 0; n < NW; ++n) {
        const f32x4 w0 = *reinterpret_cast<const f32x4*>(&wq_lds[n][col]);
        const f32x4 w1 = *reinterpret_cast<const f32x4*>(&wq_lds[n][col + 256]);
        const f32x4 w2 = *reinterpret_cast<const f32x4*>(&wq_lds[n][col + 512]);
        #pragma unroll
        for (int tt = 0; tt < TOK_PER_WAVE; ++tt)
            zf[tt][n] = dot12(xv[tt][0], xv[tt][1], xv[tt][2], w0, w1, w2);
    }

    // ---- wave reduce + cos + prefix products ----
    float z[TOK_PER_WAVE][NW];
    #pragma unroll
    for (int tt = 0; tt < TOK_PER_WAVE; ++tt)
        circuit8(zf[tt], lane, qpl, z[tt]);

    // ---- epilogue: wt fragments read ONCE per 8 tokens, plain stores ----
    #pragma unroll
    for (int k = 0; k < 3; ++k) {
        const int e0 = k * 256 + col;
        f32x4 wv[NW];
        #pragma unroll
        for (int n = 0; n < NW; ++n)
            wv[n] = *reinterpret_cast<const f32x4*>(&wt_lds[n][e0]);
        #pragma unroll
        for (int tt = 0; tt < TOK_PER_WAVE; ++tt) {
            float ox = 0.f, oy = 0.f, oz = 0.f, ow = 0.f;
            #pragma unroll
            for (int n = 0; n < NW; ++n) {
                ox += z[tt][n] * wv[n].x;
                oy += z[tt][n] * wv[n].y;
                oz += z[tt][n] * wv[n].z;
                ow += z[tt][n] * wv[n].w;
            }
            f32x4 o; o.x = ox; o.y = oy; o.z = oz; o.w = ow;
            *reinterpret_cast<f32x4*>(out + (size_t)(t0 + tt) * E + e0) = o;
        }
    }
}

extern "C" void kernel_launch(void* const* d_in, const int* in_sizes, int n_in,
                              void* d_out, int out_size, void* d_ws, size_t ws_size,
                              hipStream_t stream) {
    const float* x        = (const float*)d_in[0];
    const float* w_q      = (const float*)d_in[1];
    const float* w_out    = (const float*)d_in[2];
    const float* q_params = (const float*)d_in[3];
    float* out = (float*)d_out;

    hipLaunchKernelGGL(mhaq_kernel, dim3(GRID), dim3(BLOCK), 0, stream,
                       x, w_q, w_out, q_params, out);
}

// Round 21
// 36.606 us; speedup vs baseline: 1.4333x; 1.0801x over previous
//
#include <hip/hip_runtime.h>
#include <math.h>

// MultiHeadAttentionQuantum: analytic collapse of the 8-qubit circuit.
//   angles[t][n] = dot(x[t], w_q[n]) + q_params[n] ; c = cos(angles)
//   z[0] = c1..c7 ; z[w>=1] = c0..cw  (Heisenberg CNOT-ring push-through)
//   out[t][e] = sum_n z[n] * w_out[e][n]
//
// R21 = exact R13 (best measured: 36.1us). Full falsification matrix after
// 20 rounds: occupancy (R14/R19 clean tests: worse), store policy (plain
// wins), stream separation (R3/R18: worse), pipelining (R15-R17: flat/worse),
// fp16 weights (R11/R14: worse), token count 2/4/8 (4 optimal), staging
// locus (all-weights-LDS mandatory). All clean variants pin at 4.0-4.1 TB/s
// on this mixed 1:2 R:W + L3-hit pattern -> structural plateau.
// Config: 4 tok/wave, BLOCK 256, grid 2048, fp32 weights in 48KB LDS
// (w_out transposed), caching x loads, PLAIN stores, circuit8, bounds(256,4).

using f32x4 = __attribute__((ext_vector_type(4))) float;

constexpr int E  = 768;
constexpr int NW = 8;
constexpr int BLOCK = 256;                      // 4 waves
constexpr int TOKENS = 16 * 2048;               // 32768
constexpr int TOK_PER_WAVE  = 4;
constexpr int TOK_PER_BLOCK = TOK_PER_WAVE * 4; // 16
constexpr int GRID = TOKENS / TOK_PER_BLOCK;    // 2048

__device__ __forceinline__ float dot12(const f32x4& a0, const f32x4& a1, const f32x4& a2,
                                       const f32x4& b0, const f32x4& b1, const f32x4& b2) {
    return a0.x*b0.x + a0.y*b0.y + a0.z*b0.z + a0.w*b0.w
         + a1.x*b1.x + a1.y*b1.y + a1.z*b1.z + a1.w*b1.w
         + a2.x*b2.x + a2.y*b2.y + a2.z*b2.z + a2.w*b2.w;
}

// Wave-wide reduce of zf[0..7] + cos + CNOT-ring prefix products.
// Numerically verified R4-R20 (absmax 0.0078).
__device__ __forceinline__ void circuit8(const float zf[NW], int lane, float qpl,
                                         float z[NW]) {
    float v4[4];
    #pragma unroll
    for (int i = 0; i < 4; ++i) {
        float a = zf[2*i], b = zf[2*i+1];
        float keep = (lane & 1) ? b : a;
        float send = (lane & 1) ? a : b;
        v4[i] = keep + __shfl_xor(send, 1, 64);
    }
    float v2[2];
    #pragma unroll
    for (int i = 0; i < 2; ++i) {
        float a = v4[2*i], b = v4[2*i+1];
        float keep = (lane & 2) ? b : a;
        float send = (lane & 2) ? a : b;
        v2[i] = keep + __shfl_xor(send, 2, 64);
    }
    float a = v2[0], b = v2[1];
    float keep = (lane & 4) ? b : a;
    float send = (lane & 4) ? a : b;
    float v = keep + __shfl_xor(send, 4, 64);
    v += __shfl_xor(v, 8, 64);
    v += __shfl_xor(v, 16, 64);
    v += __shfl_xor(v, 32, 64);
    float c = __cosf(v + qpl);               // one cos per token (wire lane&7)
    float cx = __shfl_xor(c, 1, 64);
    float e0 = (lane & 1) ? cx : c;
    float e1 = (lane & 1) ? c : cx;
    float e0x = __shfl_xor(e0, 2, 64), e1x = __shfl_xor(e1, 2, 64);
    float f0 = (lane & 2) ? e0x : e0;
    float f1 = (lane & 2) ? e1x : e1;
    float f2 = (lane & 2) ? e0  : e0x;
    float f3 = (lane & 2) ? e1  : e1x;
    float f0x = __shfl_xor(f0, 4, 64), f1x = __shfl_xor(f1, 4, 64);
    float f2x = __shfl_xor(f2, 4, 64), f3x = __shfl_xor(f3, 4, 64);
    float c0 = (lane & 4) ? f0x : f0;
    float c1 = (lane & 4) ? f1x : f1;
    float c2 = (lane & 4) ? f2x : f2;
    float c3 = (lane & 4) ? f3x : f3;
    float c4 = (lane & 4) ? f0  : f0x;
    float c5 = (lane & 4) ? f1  : f1x;
    float c6 = (lane & 4) ? f2  : f2x;
    float c7 = (lane & 4) ? f3  : f3x;
    float p1 = c0*c1, p2 = p1*c2, p3 = p2*c3, p4 = p3*c4;
    float p5 = p4*c5, p6 = p5*c6, p7 = p6*c7;
    float s  = c1*c2*c3*c4*c5*c6*c7;
    z[0] = s;  z[1] = p1; z[2] = p2; z[3] = p3;
    z[4] = p4; z[5] = p5; z[6] = p6; z[7] = p7;
}

__global__ __launch_bounds__(BLOCK, 4)
void mhaq_kernel(const float* __restrict__ x,
                 const float* __restrict__ w_q,
                 const float* __restrict__ w_out,
                 const float* __restrict__ q_params,
                 float* __restrict__ out)
{
    __shared__ float wq_lds[NW][E];   // 24 KB, w_q as-is [n][e]
    __shared__ float wt_lds[NW][E];   // 24 KB, w_out transposed [n][e]

    const int tid  = threadIdx.x;
    const int wave = tid >> 6;
    const int lane = tid & 63;
    const int col  = lane * 4;
    const int t0   = blockIdx.x * TOK_PER_BLOCK + wave * TOK_PER_WAVE;

    // ---- x loads issued FIRST: HBM latency overlaps (L2-hit) staging ----
    f32x4 xv[TOK_PER_WAVE][3];
    #pragma unroll
    for (int tt = 0; tt < TOK_PER_WAVE; ++tt) {
        const f32x4* xp = reinterpret_cast<const f32x4*>(x + (size_t)(t0 + tt) * E);
        #pragma unroll
        for (int k = 0; k < 3; ++k)
            xv[tt][k] = xp[lane + k * 64];
    }

    // ---- stage weights once per block ----
    {
        const f32x4* src = reinterpret_cast<const f32x4*>(w_q);
        f32x4* dst = reinterpret_cast<f32x4*>(&wq_lds[0][0]);
        #pragma unroll
        for (int r = 0; r < (NW * E / 4) / BLOCK; ++r)
            dst[tid + r * BLOCK] = src[tid + r * BLOCK];
    }
    {
        const f32x4* src = reinterpret_cast<const f32x4*>(w_out);
        #pragma unroll
        for (int r = 0; r < (NW * E / 4) / BLOCK; ++r) {
            int idx = tid + r * BLOCK;       // f32x4 index into [768][8]
            f32x4 v = src[idx];
            int e  = idx >> 1;               // two f32x4 per e-row
            int n0 = (idx & 1) * 4;
            wt_lds[n0 + 0][e] = v.x;
            wt_lds[n0 + 1][e] = v.y;
            wt_lds[n0 + 2][e] = v.z;
            wt_lds[n0 + 3][e] = v.w;
        }
    }
    const float qpl = q_params[lane & 7];
    __syncthreads();

    // ---- per-lane partial dots (w_q from LDS) ----
    float zf[TOK_PER_WAVE][NW];
    #pragma unroll
    for (int n = 0; n < NW; ++n) {
        const f32x4 w0 = *reinterpret_cast<const f32x4*>(&wq_lds[n][col]);
        const f32x4 w1 = *reinterpret_cast<const f32x4*>(&wq_lds[n][col + 256]);
        const f32x4 w2 = *reinterpret_cast<const f32x4*>(&wq_lds[n][col + 512]);
        #pragma unroll
        for (int tt = 0; tt < TOK_PER_WAVE; ++tt)
            zf[tt][n] = dot12(xv[tt][0], xv[tt][1], xv[tt][2], w0, w1, w2);
    }

    // ---- wave reduce + cos + prefix products ----
    float z[TOK_PER_WAVE][NW];
    #pragma unroll
    for (int tt = 0; tt < TOK_PER_WAVE; ++tt)
        circuit8(zf[tt], lane, qpl, z[tt]);

    // ---- epilogue: out[t][e] = sum_n z[n] * w_out[e][n] (w_out from LDS),
    //      plain stores (write-allocate L2/L3, lazy writeback) ----
    #pragma unroll
    for (int k = 0; k < 3; ++k) {
        const int e0 = k * 256 + col;
        f32x4 wv[NW];
        #pragma unroll
        for (int n = 0; n < NW; ++n)
            wv[n] = *reinterpret_cast<const f32x4*>(&wt_lds[n][e0]);
        #pragma unroll
        for (int tt = 0; tt < TOK_PER_WAVE; ++tt) {
            float ox = 0.f, oy = 0.f, oz = 0.f, ow = 0.f;
            #pragma unroll
            for (int n = 0; n < NW; ++n) {
                ox += z[tt][n] * wv[n].x;
                oy += z[tt][n] * wv[n].y;
                oz += z[tt][n] * wv[n].z;
                ow += z[tt][n] * wv[n].w;
            }
            f32x4 o; o.x = ox; o.y = oy; o.z = oz; o.w = ow;
            *reinterpret_cast<f32x4*>(out + (size_t)(t0 + tt) * E + e0) = o;
        }
    }
}

extern "C" void kernel_launch(void* const* d_in, const int* in_sizes, int n_in,
                              void* d_out, int out_size, void* d_ws, size_t ws_size,
                              hipStream_t stream) {
    const float* x        = (const float*)d_in[0];
    const float* w_q      = (const float*)d_in[1];
    const float* w_out    = (const float*)d_in[2];
    const float* q_params = (const float*)d_in[3];
    float* out = (float*)d_out;

    hipLaunchKernelGGL(mhaq_kernel, dim3(GRID), dim3(BLOCK), 0, stream,
                       x, w_q, w_out, q_params, out);
}